// Round 1
// baseline (281.077 us; speedup 1.0000x reference)
//
#include <hip/hip_runtime.h>

typedef __attribute__((ext_vector_type(4))) short short4v;
typedef __attribute__((ext_vector_type(4))) float float4v;

#define NTOK 2048      // n = T*S
#define MROWS 4096     // B*n
#define DMODEL 512
#define NINNER 1024
#define DH 64
#define HH 16

__device__ __forceinline__ unsigned short f2bf(float f) {
    unsigned int u = __builtin_bit_cast(unsigned int, f);
    u += 0x7fffu + ((u >> 16) & 1u);
    return (unsigned short)(u >> 16);
}
__device__ __forceinline__ float bf2f(unsigned short h) {
    unsigned int u = ((unsigned int)h) << 16;
    return __builtin_bit_cast(float, u);
}

// ---- x,y + pos_emb -> bf16 ----
__global__ void k_prep(const float* __restrict__ x, const float* __restrict__ y,
                       const float* __restrict__ pe,
                       unsigned short* __restrict__ xpb, unsigned short* __restrict__ ypb) {
    int idx = blockIdx.x * blockDim.x + threadIdx.x;
    int e0 = idx * 4;
    if (e0 >= MROWS * DMODEL) return;
    int row = e0 >> 9, col = e0 & 511;
    int t = (row & (NTOK - 1)) >> 7;
    const float4v xv = *(const float4v*)(x + e0);
    const float4v yv = *(const float4v*)(y + e0);
    const float4v pv = *(const float4v*)(pe + t * DMODEL + col);
    short4v xo, yo;
#pragma unroll
    for (int i = 0; i < 4; ++i) {
        xo[i] = (short)f2bf(xv[i] + pv[i]);
        yo[i] = (short)f2bf(yv[i] + pv[i]);
    }
    *(short4v*)(xpb + e0) = xo;
    *(short4v*)(ypb + e0) = yo;
}

// ---- W[k][n] f32 -> Wt[n][k] bf16 ----
__global__ void k_wt(const float* __restrict__ W, unsigned short* __restrict__ Wt,
                     int K, int N) {
    int idx = blockIdx.x * blockDim.x + threadIdx.x;
    if (idx >= K * N) return;
    int n = idx % N, k = idx / N;
    Wt[(size_t)n * K + k] = f2bf(W[(size_t)k * N + n]);
}

// ---- RoPE cos/sin tables [2048][32] ----
__global__ void k_rtab(float* __restrict__ ct, float* __restrict__ st) {
    int idx = blockIdx.x * blockDim.x + threadIdx.x;  // 65536
    int p = idx >> 5, j = idx & 31;
    float e = (float)(2 * j) * (1.0f / 64.0f);
    float invf = powf(10000.0f, -e);
    float f = (float)p * invf;
    ct[idx] = cosf(f);
    st[idx] = sinf(f);
}

// ---- bf16 MFMA GEMM: C[M][N] = A[M][K] @ Bt[N][K]^T (+bias) ----
// block: 256 thr = 4 waves; tile 128x64, BK=32
template <int OUTF32>
__global__ __launch_bounds__(256) void k_gemm(const unsigned short* __restrict__ A,
                                              const unsigned short* __restrict__ Bt,
                                              void* __restrict__ Cv,
                                              const float* __restrict__ bias,
                                              int M, int N, int K) {
    __shared__ unsigned short As[128][36];
    __shared__ unsigned short Bs[64][36];
    const int tid = threadIdx.x;
    const int w = tid >> 6, l = tid & 63, l16 = l & 15, l4 = l >> 4;
    const int m0 = blockIdx.y * 128, n0 = blockIdx.x * 64;
    float4v acc[2][4];
#pragma unroll
    for (int i = 0; i < 2; ++i)
#pragma unroll
        for (int j = 0; j < 4; ++j) acc[i][j] = (float4v){0.f, 0.f, 0.f, 0.f};

    for (int k0 = 0; k0 < K; k0 += 32) {
        __syncthreads();
#pragma unroll
        for (int it = 0; it < 4; ++it) {
            int i = tid + it * 256;          // 0..1023
            int r = i >> 3, c4 = (i & 7) * 4;
            *(short4v*)&As[r][c4] = *(const short4v*)(A + (size_t)(m0 + r) * K + k0 + c4);
        }
#pragma unroll
        for (int it = 0; it < 2; ++it) {
            int i = tid + it * 256;          // 0..511
            int r = i >> 3, c4 = (i & 7) * 4;
            *(short4v*)&Bs[r][c4] = *(const short4v*)(Bt + (size_t)(n0 + r) * K + k0 + c4);
        }
        __syncthreads();
#pragma unroll
        for (int kk = 0; kk < 32; kk += 16) {
            short4v af[2], bf[4];
#pragma unroll
            for (int mi = 0; mi < 2; ++mi)
                af[mi] = *(const short4v*)&As[w * 32 + mi * 16 + l16][kk + l4 * 4];
#pragma unroll
            for (int nj = 0; nj < 4; ++nj)
                bf[nj] = *(const short4v*)&Bs[nj * 16 + l16][kk + l4 * 4];
#pragma unroll
            for (int mi = 0; mi < 2; ++mi)
#pragma unroll
                for (int nj = 0; nj < 4; ++nj)
                    acc[mi][nj] = __builtin_amdgcn_mfma_f32_16x16x16bf16_1k(
                        af[mi], bf[nj], acc[mi][nj], 0, 0, 0);
        }
    }
#pragma unroll
    for (int mi = 0; mi < 2; ++mi)
#pragma unroll
        for (int nj = 0; nj < 4; ++nj) {
            int col = n0 + nj * 16 + l16;
            float bv = bias ? bias[col] : 0.0f;
#pragma unroll
            for (int r = 0; r < 4; ++r) {
                int row = m0 + w * 32 + mi * 16 + l4 * 4 + r;
                float v = acc[mi][nj][r] + bv;
                if (OUTF32)
                    ((float*)Cv)[(size_t)row * N + col] = v;
                else
                    ((unsigned short*)Cv)[(size_t)row * N + col] = f2bf(v);
            }
        }
}

// ---- RoPE + head-relayout: qtmp/ktmp f32 [4096][1024] -> qh/kh bf16 [B,H,n,64] ----
__global__ void k_rope(const float* __restrict__ qt, const float* __restrict__ kt,
                       const float* __restrict__ ct, const float* __restrict__ st,
                       unsigned short* __restrict__ qh, unsigned short* __restrict__ kh) {
    int idx = blockIdx.x * blockDim.x + threadIdx.x;  // 4096*16*32
    int j = idx & 31;
    int h = (idx >> 5) & 15;
    int row = idx >> 9;
    int pos = row & (NTOK - 1);
    int b = row >> 11;
    size_t ibase = (size_t)row * NINNER + h * DH;
    float c = ct[pos * 32 + j], s = st[pos * 32 + j];
    float q1 = qt[ibase + j], q2 = qt[ibase + j + 32];
    float k1 = kt[ibase + j], k2 = kt[ibase + j + 32];
    float qo1 = q1 * c - q2 * s, qo2 = q2 * c + q1 * s;
    float ko1 = k1 * c - k2 * s, ko2 = k2 * c + k1 * s;
    const float sc = 0.125f;  // dh^-0.5 folded into q
    size_t ob = (size_t)((b * HH + h) * NTOK + pos) * DH;
    qh[ob + j] = f2bf(qo1 * sc);
    qh[ob + j + 32] = f2bf(qo2 * sc);
    kh[ob + j] = f2bf(ko1);
    kh[ob + j + 32] = f2bf(ko2);
}

// ---- v relayout: vtmp bf16 [4096][1024] -> vt bf16 [B,H,64,n] ----
__global__ void k_vt(const unsigned short* __restrict__ vtmp, unsigned short* __restrict__ vt) {
    int idx = blockIdx.x * blockDim.x + threadIdx.x;  // 4,194,304
    int pos = idx & (NTOK - 1);
    int rest = idx >> 11;
    int d = rest & 63;
    int h = (rest >> 6) & 15;
    int b = rest >> 10;
    vt[idx] = vtmp[(size_t)(b * NTOK + pos) * NINNER + h * DH + d];
}

// ---- fused masked flash attention ----
// grid: B*H*T blocks (512); 256 thr = 4 waves; wave owns 32 q-rows.
// Computes S^T = K @ Q^T so P^T lands directly in the B-frag layout for O^T = V^T @ P^T.
__global__ __launch_bounds__(256) void k_attn(const unsigned short* __restrict__ qh,
                                              const unsigned short* __restrict__ kh,
                                              const unsigned short* __restrict__ vt,
                                              const int* __restrict__ tmask,
                                              unsigned short* __restrict__ otmp) {
    int blk = blockIdx.x;
    int ti = blk & 15, h = (blk >> 4) & 15, b = blk >> 8;
    int tid = threadIdx.x;
    int w = tid >> 6, l = tid & 63, l16 = l & 15, l4 = l >> 4;
    __shared__ int msk[16];
    if (tid < 16) msk[tid] = tmask[(b * 16 + ti) * 16 + tid];
    __syncthreads();
    const unsigned short* qb = qh + (size_t)((b * HH + h) * NTOK) * DH;
    const unsigned short* kb = kh + (size_t)((b * HH + h) * NTOK) * DH;
    const unsigned short* vb = vt + (size_t)((b * HH + h) * DH) * NTOK;
    int q0 = ti * 128 + w * 32;

    short4v qf[2][4];  // B-frags of Q^T: [nq][ks]
#pragma unroll
    for (int nq = 0; nq < 2; ++nq)
#pragma unroll
        for (int ks = 0; ks < 4; ++ks)
            qf[nq][ks] = *(const short4v*)(qb + (size_t)(q0 + nq * 16 + l16) * DH + ks * 16 + l4 * 4);

    float4v oacc[4][2];  // O^T frags: [md][nq]
#pragma unroll
    for (int i = 0; i < 4; ++i)
#pragma unroll
        for (int j = 0; j < 2; ++j) oacc[i][j] = (float4v){0.f, 0.f, 0.f, 0.f};
    float mrow[2] = {-1e30f, -1e30f}, lrow[2] = {0.f, 0.f};

    for (int tj = 0; tj < 16; ++tj) {
        if (msk[tj] == 0) continue;  // whole 128x128 tile masked out
        int k0 = tj * 128;
        float4v sacc[8][2];
#pragma unroll
        for (int i = 0; i < 8; ++i)
#pragma unroll
            for (int j = 0; j < 2; ++j) sacc[i][j] = (float4v){0.f, 0.f, 0.f, 0.f};
#pragma unroll
        for (int jk = 0; jk < 8; ++jk) {
            short4v kfr[4];
#pragma unroll
            for (int ks = 0; ks < 4; ++ks)
                kfr[ks] = *(const short4v*)(kb + (size_t)(k0 + jk * 16 + l16) * DH + ks * 16 + l4 * 4);
#pragma unroll
            for (int ks = 0; ks < 4; ++ks)
#pragma unroll
                for (int nq = 0; nq < 2; ++nq)
                    sacc[jk][nq] = __builtin_amdgcn_mfma_f32_16x16x16bf16_1k(
                        kfr[ks], qf[nq][ks], sacc[jk][nq], 0, 0, 0);
        }
        // online softmax (per q-column; lane holds 32 kv values per nq)
        short4v pf[8][2];
#pragma unroll
        for (int nq = 0; nq < 2; ++nq) {
            float tm = -1e30f;
#pragma unroll
            for (int jk = 0; jk < 8; ++jk)
#pragma unroll
                for (int r = 0; r < 4; ++r) tm = fmaxf(tm, sacc[jk][nq][r]);
            tm = fmaxf(tm, __shfl_xor(tm, 16));
            tm = fmaxf(tm, __shfl_xor(tm, 32));
            float mnew = fmaxf(mrow[nq], tm);
            float alpha = __expf(mrow[nq] - mnew);
            float ts = 0.f;
#pragma unroll
            for (int jk = 0; jk < 8; ++jk) {
                short4v pv;
#pragma unroll
                for (int r = 0; r < 4; ++r) {
                    float p = __expf(sacc[jk][nq][r] - mnew);
                    ts += p;
                    pv[r] = (short)f2bf(p);
                }
                pf[jk][nq] = pv;
            }
            ts += __shfl_xor(ts, 16);
            ts += __shfl_xor(ts, 32);
            lrow[nq] = lrow[nq] * alpha + ts;
            mrow[nq] = mnew;
#pragma unroll
            for (int md = 0; md < 4; ++md)
#pragma unroll
                for (int r = 0; r < 4; ++r) oacc[md][nq][r] *= alpha;
        }
        // O^T += V^T @ P^T  (P^T already in B-frag layout)
#pragma unroll
        for (int md = 0; md < 4; ++md) {
#pragma unroll
            for (int ks = 0; ks < 8; ++ks) {
                short4v vfr = *(const short4v*)(vb + (size_t)(md * 16 + l16) * NTOK + k0 + ks * 16 + l4 * 4);
#pragma unroll
                for (int nq = 0; nq < 2; ++nq)
                    oacc[md][nq] = __builtin_amdgcn_mfma_f32_16x16x16bf16_1k(
                        vfr, pf[ks][nq], oacc[md][nq], 0, 0, 0);
            }
        }
    }
    // epilogue: normalize + write otmp[B*n][1024] (cols = h*64 + d), short4 along r->d
#pragma unroll
    for (int nq = 0; nq < 2; ++nq) {
        float inv = lrow[nq] > 0.f ? 1.0f / lrow[nq] : 0.f;
        int q = q0 + nq * 16 + l16;
#pragma unroll
        for (int md = 0; md < 4; ++md) {
            short4v o;
#pragma unroll
            for (int r = 0; r < 4; ++r) o[r] = (short)f2bf(oacc[md][nq][r] * inv);
            *(short4v*)(otmp + (size_t)(b * NTOK + q) * NINNER + h * DH + md * 16 + l4 * 4) = o;
        }
    }
}

// ---- gate: out = proj * sigmoid(proj @ gate_w + gate_b) ----
__global__ __launch_bounds__(256) void k_gate(const float* __restrict__ proj,
                                              const float* __restrict__ gw,
                                              const float* __restrict__ gb,
                                              float* __restrict__ out) {
    int row = blockIdx.x * 4 + (threadIdx.x >> 6);
    int l = threadIdx.x & 63;
    const float* pr = proj + (size_t)row * DMODEL;
    float acc = 0.f;
#pragma unroll
    for (int c = 0; c < DMODEL; c += 64) acc += pr[c + l] * gw[c + l];
#pragma unroll
    for (int off = 32; off > 0; off >>= 1) acc += __shfl_xor(acc, off);
    float g = 1.0f / (1.0f + __expf(-(acc + gb[0])));
    float* orow = out + (size_t)row * DMODEL;
#pragma unroll
    for (int c = 0; c < DMODEL; c += 64) orow[c + l] = pr[c + l] * g;
}

extern "C" void kernel_launch(void* const* d_in, const int* in_sizes, int n_in,
                              void* d_out, int out_size, void* d_ws, size_t ws_size,
                              hipStream_t stream) {
    (void)in_sizes; (void)n_in; (void)out_size; (void)ws_size;
    const float* x = (const float*)d_in[0];
    const float* y = (const float*)d_in[1];
    const int* tmask = (const int*)d_in[2];
    const float* Wq = (const float*)d_in[3];
    const float* Wk = (const float*)d_in[4];
    const float* Wv = (const float*)d_in[5];
    const float* Wo = (const float*)d_in[6];
    const float* bo = (const float*)d_in[7];
    const float* pe = (const float*)d_in[8];
    const float* gw = (const float*)d_in[9];
    const float* gb = (const float*)d_in[10];

    char* ws = (char*)d_ws;
    const size_t MB = 1u << 20;
    // layout (with lifetime-based overlays):
    unsigned short* xpb = (unsigned short*)(ws + 0);        // 4MB   [live: prep..qkv gemms]
    unsigned short* ypb = (unsigned short*)(ws + 4 * MB);   // 4MB
    unsigned short* qh  = (unsigned short*)(ws + 0);        // 8MB   [overlays xpb/ypb, written by rope]
    unsigned short* wqt = (unsigned short*)(ws + 8 * MB);   // 1MB
    unsigned short* wkt = (unsigned short*)(ws + 9 * MB);
    unsigned short* wvt = (unsigned short*)(ws + 10 * MB);
    unsigned short* wot = (unsigned short*)(ws + 11 * MB);
    float* qtmp = (float*)(ws + 12 * MB);                   // 16MB f32 [live: gemm..rope]
    unsigned short* otmp = (unsigned short*)(ws + 12 * MB); // 8MB  [overlays qtmp, written by attn]
    float* ktmp = (float*)(ws + 28 * MB);                   // 16MB f32 [live: gemm..rope]
    float* proj = (float*)(ws + 28 * MB);                   // 8MB  [overlays ktmp, written by o-gemm]
    unsigned short* vtmp = (unsigned short*)(ws + 44 * MB); // 8MB  [live: gemm..k_vt]
    unsigned short* kh   = (unsigned short*)(ws + 44 * MB); // 8MB  [overlays vtmp, written by rope AFTER k_vt]
    unsigned short* vt   = (unsigned short*)(ws + 52 * MB); // 8MB
    float* ct = (float*)(ws + 60 * MB);                     // 256KB
    float* st = (float*)(ws + 60 * MB + 256 * 1024);        // 256KB
    float* outp = (float*)d_out;

    k_prep<<<2048, 256, 0, stream>>>(x, y, pe, xpb, ypb);
    k_wt<<<2048, 256, 0, stream>>>(Wq, wqt, 512, 1024);
    k_wt<<<2048, 256, 0, stream>>>(Wk, wkt, 512, 1024);
    k_wt<<<2048, 256, 0, stream>>>(Wv, wvt, 512, 1024);
    k_wt<<<2048, 256, 0, stream>>>(Wo, wot, 1024, 512);
    k_rtab<<<256, 256, 0, stream>>>(ct, st);
    // q,k from x (bug-compatible with reference); v from y. q,k out in f32 (one bf16 rounding total).
    k_gemm<1><<<dim3(16, 32), 256, 0, stream>>>(xpb, wqt, qtmp, nullptr, 4096, 1024, 512);
    k_gemm<1><<<dim3(16, 32), 256, 0, stream>>>(xpb, wkt, ktmp, nullptr, 4096, 1024, 512);
    k_gemm<0><<<dim3(16, 32), 256, 0, stream>>>(ypb, wvt, vtmp, nullptr, 4096, 1024, 512);
    k_vt<<<16384, 256, 0, stream>>>(vtmp, vt);     // must precede k_rope (kh overlays vtmp)
    k_rope<<<8192, 256, 0, stream>>>(qtmp, ktmp, ct, st, qh, kh);
    k_attn<<<512, 256, 0, stream>>>(qh, kh, vt, tmask, otmp);
    k_gemm<1><<<dim3(8, 32), 256, 0, stream>>>(otmp, wot, proj, bo, 4096, 512, 1024);
    k_gate<<<1024, 256, 0, stream>>>(proj, gw, gb, outp);
}

// Round 2
// 156.763 us; speedup vs baseline: 1.7930x; 1.7930x over previous
//
#include <hip/hip_runtime.h>
#include <hip/hip_bf16.h>

typedef __attribute__((ext_vector_type(4))) short short4v;
typedef __attribute__((ext_vector_type(8))) short short8v;
typedef __attribute__((ext_vector_type(4))) float float4v;
typedef __attribute__((ext_vector_type(2))) unsigned int uint2v;
typedef __attribute__((ext_vector_type(4))) unsigned int uint4v;

#define NTOK 2048      // n = T*S
#define MROWS 4096     // B*n
#define DMODEL 512
#define NINNER 1024
#define DH 64
#define HH 16
#define LOG2E 1.4426950408889634f

__device__ __forceinline__ unsigned short b2s(float f) {
    __hip_bfloat16 h = __float2bfloat16(f);
    return __builtin_bit_cast(unsigned short, h);
}

__device__ __forceinline__ float4v mfma32(short8v a, short8v b, float4v c) {
    return __builtin_amdgcn_mfma_f32_16x16x32_bf16(a, b, c, 0, 0, 0);
}

__device__ __forceinline__ void gld16(const void* g, void* l) {
    __builtin_amdgcn_global_load_lds((const __attribute__((address_space(1))) void*)g,
                                     (__attribute__((address_space(3))) void*)l, 16, 0, 0);
}

// ---- x,y + pos_emb -> bf16 ----
__global__ void k_prep(const float* __restrict__ x, const float* __restrict__ y,
                       const float* __restrict__ pe,
                       unsigned short* __restrict__ xpb, unsigned short* __restrict__ ypb) {
    int idx = blockIdx.x * blockDim.x + threadIdx.x;
    int e0 = idx * 4;
    if (e0 >= MROWS * DMODEL) return;
    int row = e0 >> 9, col = e0 & 511;
    int t = (row & (NTOK - 1)) >> 7;
    const float4v xv = *(const float4v*)(x + e0);
    const float4v yv = *(const float4v*)(y + e0);
    const float4v pv = *(const float4v*)(pe + t * DMODEL + col);
    short4v xo, yo;
#pragma unroll
    for (int i = 0; i < 4; ++i) {
        xo[i] = (short)b2s(xv[i] + pv[i]);
        yo[i] = (short)b2s(yv[i] + pv[i]);
    }
    *(short4v*)(xpb + e0) = xo;
    *(short4v*)(ypb + e0) = yo;
}

// ---- fused: 4 weight transposes (f32 -> bf16, [K][N] -> [N][K]) + RoPE trig tables ----
__global__ void k_misc(const float* __restrict__ Wq, const float* __restrict__ Wk,
                       const float* __restrict__ Wv, const float* __restrict__ Wo,
                       unsigned short* __restrict__ wqt, unsigned short* __restrict__ wkt,
                       unsigned short* __restrict__ wvt, unsigned short* __restrict__ wot,
                       float* __restrict__ ctab, float* __restrict__ stab) {
    int blk = blockIdx.x;
    if (blk < 6144) {  // wq/wk/wv: [512][1024] -> [1024][512]
        int which = blk >> 11;
        int idx = (blk & 2047) * 256 + threadIdx.x;
        const float* W = (which == 0) ? Wq : (which == 1) ? Wk : Wv;
        unsigned short* Wt = (which == 0) ? wqt : (which == 1) ? wkt : wvt;
        int n = idx & 1023, k = idx >> 10;
        Wt[n * 512 + k] = b2s(W[idx]);
    } else if (blk < 8192) {  // wo: [1024][512] -> [512][1024]
        int idx = (blk - 6144) * 256 + threadIdx.x;
        int n = idx & 511, k = idx >> 9;
        wot[n * 1024 + k] = b2s(Wo[idx]);
    } else {  // rope tables [2048][32]
        int idx = (blk - 8192) * 256 + threadIdx.x;
        int p = idx >> 5, j = idx & 31;
        float invf = powf(10000.0f, -(float)(2 * j) * (1.0f / 64.0f));
        float f = (float)p * invf;
        ctab[idx] = cosf(f);
        stab[idx] = sinf(f);
    }
}

// ---- bf16 MFMA GEMM, fragment-order LDS + global_load_lds + double buffer ----
// C[M][N] = A[M][K] @ Bt[N][K]^T. tile 128x64, BK=32, 4 waves.
// EPI: 0 = f32 +bias (row-major), 1 = RoPE -> bf16 [B,H,n,64] (*scale), 2 = V^T -> bf16 [B,H,64,n]
template <int EPI>
__global__ __launch_bounds__(256) void k_gemm(const unsigned short* __restrict__ A,
                                              const unsigned short* __restrict__ Bt,
                                              void* __restrict__ Cv,
                                              const float* __restrict__ bias,
                                              const float* __restrict__ ctab,
                                              const float* __restrict__ stab,
                                              float scale, int M, int N, int K) {
    __shared__ unsigned short Ab[2][4096];  // 8 frags x (64 lanes x 8 shorts)
    __shared__ unsigned short Bb[2][2048];  // 4 frags
    const int tid = threadIdx.x;
    const int w = tid >> 6, l = tid & 63, l16 = l & 15, g = l >> 4;
    const int m0 = blockIdx.y * 128, n0 = blockIdx.x * 64;
    float4v acc[2][4];
#pragma unroll
    for (int i = 0; i < 2; ++i)
#pragma unroll
        for (int j = 0; j < 4; ++j) acc[i][j] = (float4v){0.f, 0.f, 0.f, 0.f};

    const int nstep = K >> 5;
    auto stage = [&](int t, int buf) {
        int k0 = t * 32;
#pragma unroll
        for (int s = 0; s < 2; ++s) {
            int fi = s * 4 + w;
            gld16(A + (size_t)(m0 + fi * 16 + l16) * K + k0 + g * 8, &Ab[buf][fi * 512]);
        }
        gld16(Bt + (size_t)(n0 + w * 16 + l16) * K + k0 + g * 8, &Bb[buf][w * 512]);
    };

    stage(0, 0);
    __syncthreads();
    for (int t = 0; t < nstep; ++t) {
        const int cur = t & 1;
        if (t + 1 < nstep) stage(t + 1, cur ^ 1);
        short8v af[2], bf[4];
#pragma unroll
        for (int mi = 0; mi < 2; ++mi)
            af[mi] = *(const short8v*)&Ab[cur][(w * 2 + mi) * 512 + l * 8];
#pragma unroll
        for (int nj = 0; nj < 4; ++nj)
            bf[nj] = *(const short8v*)&Bb[cur][nj * 512 + l * 8];
        __builtin_amdgcn_s_setprio(1);
#pragma unroll
        for (int mi = 0; mi < 2; ++mi)
#pragma unroll
            for (int nj = 0; nj < 4; ++nj)
                acc[mi][nj] = mfma32(af[mi], bf[nj], acc[mi][nj]);
        __builtin_amdgcn_s_setprio(0);
        __syncthreads();  // drains vmcnt (prefetch) + lgkmcnt before buffer swap
    }

    if (EPI == 0) {
#pragma unroll
        for (int mi = 0; mi < 2; ++mi)
#pragma unroll
            for (int nj = 0; nj < 4; ++nj) {
                int col = n0 + nj * 16 + l16;
                float bv = bias ? bias[col] : 0.0f;
#pragma unroll
                for (int r = 0; r < 4; ++r) {
                    int row = m0 + w * 32 + mi * 16 + g * 4 + r;
                    ((float*)Cv)[(size_t)row * N + col] = acc[mi][nj][r] + bv;
                }
            }
    } else if (EPI == 1) {  // RoPE: cols n0..n0+63 = one head; pairs (j, j+32) in-lane
        const int hh = n0 >> 6;
        unsigned short* out = (unsigned short*)Cv;
#pragma unroll
        for (int mi = 0; mi < 2; ++mi)
#pragma unroll
            for (int r = 0; r < 4; ++r) {
                int row = m0 + w * 32 + mi * 16 + g * 4 + r;
                int b = row >> 11, pos = row & (NTOK - 1);
                const float* cr = ctab + pos * 32;
                const float* sr = stab + pos * 32;
                unsigned short* ob = out + (size_t)((b * HH + hh) * NTOK + pos) * DH;
#pragma unroll
                for (int nj = 0; nj < 2; ++nj) {
                    int j = nj * 16 + l16;
                    float c = cr[j], s = sr[j];
                    float v1 = acc[mi][nj][r], v2 = acc[mi][nj + 2][r];
                    ob[j] = b2s((v1 * c - v2 * s) * scale);
                    ob[j + 32] = b2s((v2 * c + v1 * s) * scale);
                }
            }
    } else {  // EPI == 2: V^T layout [B,H,64,n]
        const int hh = n0 >> 6;
        unsigned short* out = (unsigned short*)Cv;
#pragma unroll
        for (int mi = 0; mi < 2; ++mi)
#pragma unroll
            for (int nj = 0; nj < 4; ++nj) {
                int d = nj * 16 + l16;
                int row0 = m0 + w * 32 + mi * 16 + g * 4;
                int b = row0 >> 11, pos0 = row0 & (NTOK - 1);
                short4v o;
#pragma unroll
                for (int r = 0; r < 4; ++r) o[r] = (short)b2s(acc[mi][nj][r]);
                *(short4v*)(out + (size_t)((b * HH + hh) * DH + d) * NTOK + pos0) = o;
            }
    }
}

// ---- fused masked flash attention v2 ----
// grid: B*H*T (512) blocks; 4 waves; wave owns 32 q-rows. S^T = K@Q^T; O^T = V^T@P^T.
// K staged via global_load_lds in fragment order (conflict-free); V reg-staged in
// P-matching fragment order (kv slot = {g*4+j, 16+g*4+j} per 32-chunk) -> no shuffles.
__global__ __launch_bounds__(256, 2) void k_attn(const unsigned short* __restrict__ qh,
                                                 const unsigned short* __restrict__ kh,
                                                 const unsigned short* __restrict__ vt,
                                                 const int* __restrict__ tmask,
                                                 unsigned short* __restrict__ otmp) {
    __shared__ unsigned short Kb[2][8192];  // 16 frags x 512 shorts
    __shared__ unsigned short Vb[8192];
    __shared__ int tlist[17];
    const int blk = blockIdx.x;
    const int ti = blk & 15, h = (blk >> 4) & 15, b = blk >> 8;
    const int tid = threadIdx.x, w = tid >> 6, l = tid & 63, l16 = l & 15, g = l >> 4;
    if (tid == 0) {
        int c = 0;
        for (int j = 0; j < 16; ++j)
            if (tmask[(b * 16 + ti) * 16 + j]) tlist[c++] = j;
        tlist[16] = c;
    }
    __syncthreads();
    const int cnt = tlist[16];
    const unsigned short* qb = qh + (size_t)((b * HH + h) * NTOK) * DH;
    const unsigned short* kb = kh + (size_t)((b * HH + h) * NTOK) * DH;
    const unsigned short* vb = vt + (size_t)((b * HH + h) * DH) * NTOK;
    const int q0 = ti * 128 + w * 32;

    short8v qf[2][2];
#pragma unroll
    for (int nq = 0; nq < 2; ++nq)
#pragma unroll
        for (int c = 0; c < 2; ++c)
            qf[nq][c] = *(const short8v*)(qb + (size_t)(q0 + nq * 16 + l16) * DH + c * 32 + g * 8);

    float4v oacc[4][2];
#pragma unroll
    for (int i = 0; i < 4; ++i)
#pragma unroll
        for (int j = 0; j < 2; ++j) oacc[i][j] = (float4v){0.f, 0.f, 0.f, 0.f};
    float mrow[2] = {-1e30f, -1e30f}, lrow[2] = {0.f, 0.f};
    uint2v vrg[4][2];

    auto stageK = [&](int tj, int buf) {
#pragma unroll
        for (int s = 0; s < 4; ++s) {
            int fi = s * 4 + w;  // frag (jk = fi>>1, c = fi&1)
            const unsigned short* ga =
                kb + (size_t)(tj * 128 + (fi >> 1) * 16 + l16) * DH + (fi & 1) * 32 + g * 8;
            gld16(ga, &Kb[buf][fi * 512]);
        }
    };
    auto loadV = [&](int tj) {
#pragma unroll
        for (int s = 0; s < 4; ++s) {  // vfi = s*4+w: md = s, cc = w
            const unsigned short* ga = vb + (size_t)(s * 16 + l16) * NTOK + tj * 128 + w * 32 + g * 4;
            vrg[s][0] = *(const uint2v*)ga;
            vrg[s][1] = *(const uint2v*)(ga + 16);
        }
    };
    auto writeV = [&]() {
#pragma unroll
        for (int s = 0; s < 4; ++s) {
            uint4v val = {vrg[s][0][0], vrg[s][0][1], vrg[s][1][0], vrg[s][1][1]};
            *(uint4v*)&Vb[(s * 4 + w) * 512 + l * 8] = val;
        }
    };

    if (cnt > 0) {
        stageK(tlist[0], 0);
        loadV(tlist[0]);
        writeV();
        __syncthreads();
        for (int i = 0; i < cnt; ++i) {
            const int cur = i & 1;
            const bool pre = (i + 1 < cnt);
            if (pre) { stageK(tlist[i + 1], cur ^ 1); loadV(tlist[i + 1]); }
            // ---- QK^T ----
            float4v sacc[8][2];
#pragma unroll
            for (int jk = 0; jk < 8; ++jk)
#pragma unroll
                for (int nq = 0; nq < 2; ++nq) sacc[jk][nq] = (float4v){0.f, 0.f, 0.f, 0.f};
            __builtin_amdgcn_s_setprio(1);
#pragma unroll
            for (int jk = 0; jk < 8; ++jk) {
                short8v kf0 = *(const short8v*)&Kb[cur][(jk * 2 + 0) * 512 + l * 8];
                short8v kf1 = *(const short8v*)&Kb[cur][(jk * 2 + 1) * 512 + l * 8];
#pragma unroll
                for (int nq = 0; nq < 2; ++nq) {
                    sacc[jk][nq] = mfma32(kf0, qf[nq][0], sacc[jk][nq]);
                    sacc[jk][nq] = mfma32(kf1, qf[nq][1], sacc[jk][nq]);
                }
            }
            __builtin_amdgcn_s_setprio(0);
            // ---- online softmax (base-2; log2e folded into q scale) ----
            short8v pf[4][2];
#pragma unroll
            for (int nq = 0; nq < 2; ++nq) {
                float tm = -1e30f;
#pragma unroll
                for (int jk = 0; jk < 8; ++jk)
#pragma unroll
                    for (int r = 0; r < 4; ++r) tm = fmaxf(tm, sacc[jk][nq][r]);
                tm = fmaxf(tm, __shfl_xor(tm, 16));
                tm = fmaxf(tm, __shfl_xor(tm, 32));
                float mnew = fmaxf(mrow[nq], tm);
                float alpha = exp2f(mrow[nq] - mnew);
                float ts = 0.f;
#pragma unroll
                for (int cc = 0; cc < 4; ++cc) {
                    short8v pv;
#pragma unroll
                    for (int r = 0; r < 4; ++r) {
                        float p0 = exp2f(sacc[2 * cc][nq][r] - mnew);
                        float p1 = exp2f(sacc[2 * cc + 1][nq][r] - mnew);
                        ts += p0 + p1;
                        pv[r] = (short)b2s(p0);
                        pv[r + 4] = (short)b2s(p1);
                    }
                    pf[cc][nq] = pv;
                }
                ts += __shfl_xor(ts, 16);
                ts += __shfl_xor(ts, 32);
                lrow[nq] = lrow[nq] * alpha + ts;
                mrow[nq] = mnew;
#pragma unroll
                for (int md = 0; md < 4; ++md)
#pragma unroll
                    for (int r = 0; r < 4; ++r) oacc[md][nq][r] *= alpha;
            }
            // ---- O^T += V^T @ P^T ----
            __builtin_amdgcn_s_setprio(1);
#pragma unroll
            for (int md = 0; md < 4; ++md)
#pragma unroll
                for (int cc = 0; cc < 4; ++cc) {
                    short8v vf = *(const short8v*)&Vb[(md * 4 + cc) * 512 + l * 8];
#pragma unroll
                    for (int nq = 0; nq < 2; ++nq)
                        oacc[md][nq] = mfma32(vf, pf[cc][nq], oacc[md][nq]);
                }
            __builtin_amdgcn_s_setprio(0);
            __syncthreads();  // drains prefetch vmcnt; all waves done reading Vb
            if (pre) writeV();
            __syncthreads();
        }
    }
#pragma unroll
    for (int nq = 0; nq < 2; ++nq) {
        float inv = lrow[nq] > 0.f ? 1.0f / lrow[nq] : 0.f;
        int q = q0 + nq * 16 + l16;
#pragma unroll
        for (int md = 0; md < 4; ++md) {
            short4v o;
#pragma unroll
            for (int r = 0; r < 4; ++r) o[r] = (short)b2s(oacc[md][nq][r] * inv);
            *(short4v*)(otmp + (size_t)(b * NTOK + q) * NINNER + h * DH + md * 16 + g * 4) = o;
        }
    }
}

// ---- gate: out = proj * sigmoid(proj @ gate_w + gate_b) ----
__global__ __launch_bounds__(256) void k_gate(const float* __restrict__ proj,
                                              const float* __restrict__ gw,
                                              const float* __restrict__ gb,
                                              float* __restrict__ out) {
    int row = blockIdx.x * 4 + (threadIdx.x >> 6);
    int l = threadIdx.x & 63;
    const float* pr = proj + (size_t)row * DMODEL;
    float acc = 0.f;
#pragma unroll
    for (int c = 0; c < DMODEL; c += 64) acc += pr[c + l] * gw[c + l];
#pragma unroll
    for (int off = 32; off > 0; off >>= 1) acc += __shfl_xor(acc, off);
    float gt = 1.0f / (1.0f + __expf(-(acc + gb[0])));
    float* orow = out + (size_t)row * DMODEL;
#pragma unroll
    for (int c = 0; c < DMODEL; c += 64) orow[c + l] = pr[c + l] * gt;
}

extern "C" void kernel_launch(void* const* d_in, const int* in_sizes, int n_in,
                              void* d_out, int out_size, void* d_ws, size_t ws_size,
                              hipStream_t stream) {
    (void)in_sizes; (void)n_in; (void)out_size; (void)ws_size;
    const float* x = (const float*)d_in[0];
    const float* y = (const float*)d_in[1];
    const int* tmask = (const int*)d_in[2];
    const float* Wq = (const float*)d_in[3];
    const float* Wk = (const float*)d_in[4];
    const float* Wv = (const float*)d_in[5];
    const float* Wo = (const float*)d_in[6];
    const float* bo = (const float*)d_in[7];
    const float* pe = (const float*)d_in[8];
    const float* gw = (const float*)d_in[9];
    const float* gb = (const float*)d_in[10];

    char* ws = (char*)d_ws;
    const size_t MB = 1u << 20;
    unsigned short* xpb = (unsigned short*)(ws + 0);         // 4MB
    unsigned short* ypb = (unsigned short*)(ws + 4 * MB);    // 4MB
    unsigned short* wqt = (unsigned short*)(ws + 8 * MB);    // 1MB each
    unsigned short* wkt = (unsigned short*)(ws + 9 * MB);
    unsigned short* wvt = (unsigned short*)(ws + 10 * MB);
    unsigned short* wot = (unsigned short*)(ws + 11 * MB);
    unsigned short* qh  = (unsigned short*)(ws + 12 * MB);   // 8MB  [B,H,n,64] bf16
    unsigned short* kh  = (unsigned short*)(ws + 20 * MB);   // 8MB
    unsigned short* vt  = (unsigned short*)(ws + 28 * MB);   // 8MB  [B,H,64,n] bf16
    unsigned short* otm = (unsigned short*)(ws + 36 * MB);   // 8MB  [B*n,1024] bf16
    float* proj = (float*)(ws + 44 * MB);                    // 8MB  f32
    float* ct = (float*)(ws + 52 * MB);                      // 256KB
    float* st = (float*)(ws + 52 * MB + 256 * 1024);         // 256KB
    float* outp = (float*)d_out;

    k_prep<<<2048, 256, 0, stream>>>(x, y, pe, xpb, ypb);
    k_misc<<<8448, 256, 0, stream>>>(Wq, Wk, Wv, Wo, wqt, wkt, wvt, wot, ct, st);
    // q,k from x (bug-compatible with reference); v from y.
    k_gemm<1><<<dim3(16, 32), 256, 0, stream>>>(xpb, wqt, qh, nullptr, ct, st,
                                                0.125f * LOG2E, 4096, 1024, 512);
    k_gemm<1><<<dim3(16, 32), 256, 0, stream>>>(xpb, wkt, kh, nullptr, ct, st,
                                                1.0f, 4096, 1024, 512);
    k_gemm<2><<<dim3(16, 32), 256, 0, stream>>>(ypb, wvt, vt, nullptr, nullptr, nullptr,
                                                1.0f, 4096, 1024, 512);
    k_attn<<<512, 256, 0, stream>>>(qh, kh, vt, tmask, otm);
    k_gemm<0><<<dim3(8, 32), 256, 0, stream>>>(otm, wot, proj, bo, nullptr, nullptr,
                                               1.0f, 4096, 512, 1024);
    k_gate<<<1024, 256, 0, stream>>>(proj, gw, gb, outp);
}